// Round 2
// baseline (155.676 us; speedup 1.0000x reference)
//
#include <hip/hip_runtime.h>

// out[i] = sum_k coeffs[k] * R_{n_k l_k}(r) * Y_{l_k m_k}(theta, phi)
// position: (OutN*n, 3) interleaved (r, theta, phi), fp32. Output fp32.
//
// R2b: streaming-path rework (R2 + compile fix: nontemporal store needs a
// clang native vector type, not HIP_vector_type float4).
// rocprof R0 showed the kernel dispatch is below the harness's 58-60us
// re-poison fills, i.e. ~33us @ ~4 TB/s effective vs a 21.3us floor
// (134.2 MB at 6.3 TB/s). Changes vs R0:
//   - global->LDS staging via __builtin_amdgcn_global_load_lds width=16
//     (no VGPR round-trip; compiler never auto-emits this).
//   - per-wave LDS chunks, NO __syncthreads: visibility via counted
//     s_waitcnt vmcnt(N) (vmcnt(3) -> sub-chunk 0 computes while sub-chunk 1
//     is in flight; vmcnt(1) before sub-chunk 1 excludes the in-flight store,
//     VMEM retires in order).
//   - 2048 pts/block = 24 KB LDS (6 blocks/CU), 6x 1KiB loads in flight/wave.
//   - per-lane LDS read stride kept at 48 B (12 dwords): each 8-lane group
//     covers all 32 banks exactly once -> ds_read_b128 conflict-free.
//   - nontemporal stores on the write-once output.
//
// Radial norms (a0=1) folded to decimals:
//   R10 = 2 e^{-r}
//   R20 = 0.35355339059 e^{-r/2} (2 - r)
//   R21 = 0.20412414523 e^{-r/2} r
//   R30 = 0.12830005982 e^{-r/3} (3 - 2r + (2/9) r^2)
//   R31 = 0.04536092116 e^{-r/3} r (8/3 - (4/9) r)
//   R32 = 0.00901600915 e^{-r/3} r^2
// Real SH (Condon-Shortley folded):
//   Y00 = 0.28209479177 ; Y10 = 0.48860251190 ct
//   Y1,+-1 = -0.48860251190 st {sin,cos}(phi)
//   Y20 = 0.94617469575 ct^2 - 0.31539156525
//   Y2,+-1 = -1.09254843059 ct st {sin,cos}(phi)
//   Y2,+-2 = 0.54627421529 st^2 {sin,cos}(2 phi)

typedef float f32x4 __attribute__((ext_vector_type(4)));

#define GLD_LDS16(gptr, lptr)                                                  \
    __builtin_amdgcn_global_load_lds(                                          \
        (const __attribute__((address_space(1))) void*)(gptr),                 \
        (__attribute__((address_space(3))) void*)(lptr), 16, 0, 0)

__device__ __forceinline__ float eval_point(float r, float theta, float phi,
                                            const float* __restrict__ c) {
    float st, ct;
    __sincosf(theta, &st, &ct);
    float sp, cp;
    __sincosf(phi, &sp, &cp);
    const float s2p = 2.0f * sp * cp;
    const float c2p = 2.0f * cp * cp - 1.0f;

    const float ex  = __expf(r * (-1.0f / 6.0f));
    const float ex2 = ex * ex;
    const float ex3 = ex2 * ex;
    const float e1  = ex3 * ex3;   // e^{-r}
    const float e2  = ex3;         // e^{-r/2}
    const float e3  = ex2;         // e^{-r/3}

    const float R10 = 2.0f * e1;
    const float R20 = 0.35355339059f * e2 * (2.0f - r);
    const float R21 = 0.20412414523f * e2 * r;
    const float R30 = 0.12830005982f * e3 * (3.0f + r * (-2.0f + 0.22222222222f * r));
    const float R31 = 0.04536092116f * e3 * r * (2.66666666667f - 0.44444444444f * r);
    const float R32 = 0.00901600915f * e3 * r * r;

    float acc = 0.28209479177f * (c[0] * R10 + c[1] * R20 + c[5] * R30);
    acc += 0.48860251190f * ct * (c[3] * R21 + c[7] * R31);
    acc -= 0.48860251190f * st * (sp * (c[2] * R21 + c[6] * R31)
                                + cp * (c[4] * R21 + c[8] * R31));
    const float y20 = 0.94617469575f * ct * ct - 0.31539156525f;
    acc += R32 * (c[11] * y20
                  - 1.09254843059f * ct * st * (c[10] * sp + c[12] * cp)
                  + 0.54627421529f * st * st * (c[9] * s2p + c[13] * c2p));
    return acc;
}

// Each block: 256 threads, 2048 points, 24 KB LDS.
// Wave w owns points [blk*2048 + w*512, +512) = float4s [blk*1536 + w*384, +384).
// Two sub-chunks of 256 points each; within a sub-chunk lane l evaluates
// points l*4..l*4+3 (floats 12l..12l+11, the conflict-free 48B stride).
__global__ __launch_bounds__(256) void orbitals_wave(
    const float4* __restrict__ pos4,   // position viewed as float4
    const float* __restrict__ coeffs,  // 14 floats
    float4* __restrict__ out4)
{
    __shared__ float4 smem[1536];      // 24 KB: 4 waves x 384 float4
    const int t    = threadIdx.x;
    const int lane = t & 63;
    const int w    = t >> 6;

    // Uniform coeff reads -> s_load (lgkmcnt), kept out of the vmcnt queue.
    float c[14];
#pragma unroll
    for (int k = 0; k < 14; ++k) c[k] = coeffs[k];

    const float4* gsrc = pos4 + (size_t)blockIdx.x * 1536 + w * 384 + lane;
    float4* ldst = &smem[w * 384];     // wave-uniform LDS base (HW adds lane*16)

    // 6 async 16B global->LDS stages: 1 KiB/wave/instr, linear dest.
#pragma unroll
    for (int j = 0; j < 6; ++j)
        GLD_LDS16(gsrc + j * 64, ldst + j * 64);

    const int outBase = blockIdx.x * 512 + w * 128 + lane;
    const int rbase   = w * 384 + 3 * lane;
    f32x4* __restrict__ outv = (f32x4*)out4;

    // Sub-chunk 0: stages 0-2 landed once <=3 VMEM ops remain outstanding.
    asm volatile("s_waitcnt vmcnt(3)" ::: "memory");
    __builtin_amdgcn_sched_barrier(0);
    {
        const float4 a = smem[rbase + 0];
        const float4 b = smem[rbase + 1];
        const float4 d = smem[rbase + 2];
        f32x4 o;
        o.x = eval_point(a.x, a.y, a.z, c);
        o.y = eval_point(a.w, b.x, b.y, c);
        o.z = eval_point(b.z, b.w, d.x, c);
        o.w = eval_point(d.y, d.z, d.w, c);
        __builtin_nontemporal_store(o, &outv[outBase]);
    }

    // Sub-chunk 1: outstanding queue (in order) = {s3,s4,s5,store}; vmcnt(1)
    // drains the three remaining stages without waiting on the store.
    asm volatile("s_waitcnt vmcnt(1)" ::: "memory");
    __builtin_amdgcn_sched_barrier(0);
    {
        const float4 a = smem[rbase + 192 + 0];
        const float4 b = smem[rbase + 192 + 1];
        const float4 d = smem[rbase + 192 + 2];
        f32x4 o;
        o.x = eval_point(a.x, a.y, a.z, c);
        o.y = eval_point(a.w, b.x, b.y, c);
        o.z = eval_point(b.z, b.w, d.x, c);
        o.w = eval_point(d.y, d.z, d.w, c);
        __builtin_nontemporal_store(o, &outv[outBase + 64]);
    }
}

__global__ void orbitals_tail(
    const float* __restrict__ pos,
    const float* __restrict__ coeffs,
    float* __restrict__ out,
    int start, int total)
{
    const int i = start + blockIdx.x * blockDim.x + threadIdx.x;
    if (i >= total) return;
    out[i] = eval_point(pos[3 * i + 0], pos[3 * i + 1], pos[3 * i + 2], coeffs);
}

extern "C" void kernel_launch(void* const* d_in, const int* in_sizes, int n_in,
                              void* d_out, int out_size, void* d_ws, size_t ws_size,
                              hipStream_t stream) {
    const float* pos    = (const float*)d_in[0];
    const float* coeffs = (const float*)d_in[1];
    float* out = (float*)d_out;

    const int total = out_size;                 // 8,388,608 = 4096 * 2048
    const int full_blocks = total / 2048;       // blocks of 2048 elements
    const int done = full_blocks * 2048;
    const int rem = total - done;

    if (full_blocks > 0) {
        orbitals_wave<<<full_blocks, 256, 0, stream>>>(
            (const float4*)pos, coeffs, (float4*)out);
    }
    if (rem > 0) {
        const int block = 256;
        const int grid = (rem + block - 1) / block;
        orbitals_tail<<<grid, block, 0, stream>>>(pos, coeffs, out, done, total);
    }
}

// Round 3
// 153.295 us; speedup vs baseline: 1.0155x; 1.0155x over previous
//
#include <hip/hip_runtime.h>

// out[i] = sum_k coeffs[k] * R_{n_k l_k}(r) * Y_{l_k m_k}(theta, phi)
// position: (OutN*n, 3) interleaved (r, theta, phi), fp32. Output fp32.
//
// R3: occupancy restore + store-path revert (discriminating experiment).
// R2b (async gld_lds, 2048 pts/block = 24KB LDS = 6 blocks/CU, NT stores)
// was neutral-to-slightly-worse vs R0 (155.7 vs 153.3): staging style is
// not the lever (T14 null: BW-bound streaming at high occupancy). Two
// un-ablated R2b regressions remain: occupancy 32->24 waves/CU, and NT
// stores bypassing the L2 write path (the 6.8 TB/s harness fills go
// THROUGH L2). R3 keeps gld_lds staging + barrier-free per-wave waits but:
//   - 1024 pts/block -> 12 KB LDS -> 8 blocks/CU (32 waves/CU),
//     __launch_bounds__(256, 8) pins VGPR <= 64 (live set ~40; coeffs
//     become s_loads -> SGPRs).
//   - normal float4 stores (L2 write path) instead of nontemporal.
// If this lands at 153+-2 too, the kernel is at the mixed-R/W BW ceiling
// (134.2 MB irreducible; ~118 us of timed harness fills are fixed) ->
// roofline.
//
// Radial norms (a0=1) folded to decimals:
//   R10 = 2 e^{-r}
//   R20 = 0.35355339059 e^{-r/2} (2 - r)
//   R21 = 0.20412414523 e^{-r/2} r
//   R30 = 0.12830005982 e^{-r/3} (3 - 2r + (2/9) r^2)
//   R31 = 0.04536092116 e^{-r/3} r (8/3 - (4/9) r)
//   R32 = 0.00901600915 e^{-r/3} r^2
// Real SH (Condon-Shortley folded):
//   Y00 = 0.28209479177 ; Y10 = 0.48860251190 ct
//   Y1,+-1 = -0.48860251190 st {sin,cos}(phi)
//   Y20 = 0.94617469575 ct^2 - 0.31539156525
//   Y2,+-1 = -1.09254843059 ct st {sin,cos}(phi)
//   Y2,+-2 = 0.54627421529 st^2 {sin,cos}(2 phi)

#define GLD_LDS16(gptr, lptr)                                                  \
    __builtin_amdgcn_global_load_lds(                                          \
        (const __attribute__((address_space(1))) void*)(gptr),                 \
        (__attribute__((address_space(3))) void*)(lptr), 16, 0, 0)

__device__ __forceinline__ float eval_point(float r, float theta, float phi,
                                            const float* __restrict__ c) {
    float st, ct;
    __sincosf(theta, &st, &ct);
    float sp, cp;
    __sincosf(phi, &sp, &cp);
    const float s2p = 2.0f * sp * cp;
    const float c2p = 2.0f * cp * cp - 1.0f;

    const float ex  = __expf(r * (-1.0f / 6.0f));
    const float ex2 = ex * ex;
    const float ex3 = ex2 * ex;
    const float e1  = ex3 * ex3;   // e^{-r}
    const float e2  = ex3;         // e^{-r/2}
    const float e3  = ex2;         // e^{-r/3}

    const float R10 = 2.0f * e1;
    const float R20 = 0.35355339059f * e2 * (2.0f - r);
    const float R21 = 0.20412414523f * e2 * r;
    const float R30 = 0.12830005982f * e3 * (3.0f + r * (-2.0f + 0.22222222222f * r));
    const float R31 = 0.04536092116f * e3 * r * (2.66666666667f - 0.44444444444f * r);
    const float R32 = 0.00901600915f * e3 * r * r;

    float acc = 0.28209479177f * (c[0] * R10 + c[1] * R20 + c[5] * R30);
    acc += 0.48860251190f * ct * (c[3] * R21 + c[7] * R31);
    acc -= 0.48860251190f * st * (sp * (c[2] * R21 + c[6] * R31)
                                + cp * (c[4] * R21 + c[8] * R31));
    const float y20 = 0.94617469575f * ct * ct - 0.31539156525f;
    acc += R32 * (c[11] * y20
                  - 1.09254843059f * ct * st * (c[10] * sp + c[12] * cp)
                  + 0.54627421529f * st * st * (c[9] * s2p + c[13] * c2p));
    return acc;
}

// Each block: 256 threads, 1024 points, 12 KB LDS, 8 blocks/CU.
// Wave w owns points [blk*1024 + w*256, +256) = float4s [blk*768 + w*192, +192).
// Lane l evaluates points l*4..l*4+3 of its wave chunk (floats 12l..12l+11,
// the 48B-stride read: each 8-lane group covers all 32 banks exactly once ->
// ds_read_b128 conflict-free).
__global__ __launch_bounds__(256, 8) void orbitals_wave(
    const float4* __restrict__ pos4,   // position viewed as float4
    const float* __restrict__ coeffs,  // 14 floats
    float4* __restrict__ out4)
{
    __shared__ float4 smem[768];       // 12 KB: 4 waves x 192 float4
    const int t    = threadIdx.x;
    const int lane = t & 63;
    const int w    = t >> 6;

    // Uniform coeff reads -> s_load (lgkmcnt), kept out of the vmcnt queue.
    float c[14];
#pragma unroll
    for (int k = 0; k < 14; ++k) c[k] = coeffs[k];

    const float4* gsrc = pos4 + (size_t)blockIdx.x * 768 + w * 192 + lane;
    float4* ldst = &smem[w * 192];     // wave-uniform LDS base (HW adds lane*16)

    // 3 async 16B global->LDS stages: 1 KiB/wave/instr, linear dest.
#pragma unroll
    for (int j = 0; j < 3; ++j)
        GLD_LDS16(gsrc + j * 64, ldst + j * 64);

    // Per-wave wait only; waves are independent, no __syncthreads.
    asm volatile("s_waitcnt vmcnt(0)" ::: "memory");
    __builtin_amdgcn_sched_barrier(0);

    const int rbase = w * 192 + 3 * lane;
    const float4 a = smem[rbase + 0];
    const float4 b = smem[rbase + 1];
    const float4 d = smem[rbase + 2];

    float4 o;
    o.x = eval_point(a.x, a.y, a.z, c);
    o.y = eval_point(a.w, b.x, b.y, c);
    o.z = eval_point(b.z, b.w, d.x, c);
    o.w = eval_point(d.y, d.z, d.w, c);
    out4[blockIdx.x * 256 + w * 64 + lane] = o;   // coalesced 16 B/lane store
}

__global__ void orbitals_tail(
    const float* __restrict__ pos,
    const float* __restrict__ coeffs,
    float* __restrict__ out,
    int start, int total)
{
    const int i = start + blockIdx.x * blockDim.x + threadIdx.x;
    if (i >= total) return;
    out[i] = eval_point(pos[3 * i + 0], pos[3 * i + 1], pos[3 * i + 2], coeffs);
}

extern "C" void kernel_launch(void* const* d_in, const int* in_sizes, int n_in,
                              void* d_out, int out_size, void* d_ws, size_t ws_size,
                              hipStream_t stream) {
    const float* pos    = (const float*)d_in[0];
    const float* coeffs = (const float*)d_in[1];
    float* out = (float*)d_out;

    const int total = out_size;                 // 8,388,608
    const int full_blocks = total / 1024;       // blocks of 1024 elements
    const int done = full_blocks * 1024;
    const int rem = total - done;

    if (full_blocks > 0) {
        orbitals_wave<<<full_blocks, 256, 0, stream>>>(
            (const float4*)pos, coeffs, (float4*)out);
    }
    if (rem > 0) {
        const int block = 256;
        const int grid = (rem + block - 1) / block;
        orbitals_tail<<<grid, block, 0, stream>>>(pos, coeffs, out, done, total);
    }
}